// Round 1
// baseline (487.558 us; speedup 1.0000x reference)
//
#include <hip/hip_runtime.h>
#include <hip/hip_bf16.h>

typedef __attribute__((ext_vector_type(8))) short bf16x8;   // 8 bf16 = 4 VGPRs
typedef __attribute__((ext_vector_type(4))) float f32x4;    // MFMA C/D frag

#define Qn 4096
#define Mn 8192
#define Dn 128
#define NWA 4                    // waves per block
#define MSPLIT 8                 // M split across XCD-pinned block groups
#define BCOLS (Mn / MSPLIT)      // 1024 cols per block
#define WCOLS (BCOLS / NWA)      // 256 cols per wave
#define NT 64                    // cols per iteration
#define NIT (WCOLS / NT)         // 4 iterations per wave

__device__ __forceinline__ unsigned short f2bf(float x) {
  __hip_bfloat16 h = __float2bfloat16(x);
  return *reinterpret_cast<unsigned short*>(&h);
}

__global__ void zero_kernel(float4* __restrict__ p, int n4) {
  int i = blockIdx.x * blockDim.x + threadIdx.x;
  if (i < n4) p[i] = make_float4(0.f, 0.f, 0.f, 0.f);
}

// Q * (1/sqrt(D)) -> bf16, vectorized
__global__ void cast_q(const float4* __restrict__ Q4, ushort4* __restrict__ Qs) {
  int i = blockIdx.x * blockDim.x + threadIdx.x;   // < Qn*Dn/4
  const float s = 0.088388347648318447f;           // 1/sqrt(128)
  float4 q = Q4[i];
  Qs[i] = make_ushort4(f2bf(q.x * s), f2bf(q.y * s), f2bf(q.z * s), f2bf(q.w * s));
}

// Swizzle K into MFMA-fragment-major bf16 layouts so the attn inner loop's
// B-fragment loads are contiguous 1KB per wave instruction (proven R5):
//  Kswz (S=QK^T B-frag):  K[m][d] -> [((m>>4)*4 + (d>>5))*64 + lane][j]
//                         lane = ((d>>3)&3)*16 + (m&15), j = d&7
//  Vswz (PV B-frag, V^T): K[m][d] -> [(((m>>6)*8 + (d>>4))*2 + ((m&63)>>5))*64 + lane][j]
//                         lane = (((m&63)>>3)&3)*16 + (d&15), j = m&7
__global__ __launch_bounds__(256) void swz_kernel(const float* __restrict__ K,
                                                  unsigned short* __restrict__ Kswz,
                                                  unsigned short* __restrict__ Vswz) {
  __shared__ __align__(16) unsigned short T[64][72];   // 64m x 64d tile, bf16, padded
  const int m0 = blockIdx.x * 64, d0 = blockIdx.y * 64;
  const int t = threadIdx.x;
  const int r = t >> 4, c4 = (t & 15) * 4;
#pragma unroll
  for (int rr = 0; rr < 64; rr += 16) {
    float4 v = *reinterpret_cast<const float4*>(&K[(size_t)(m0 + r + rr) * Dn + d0 + c4]);
    ushort4 b = make_ushort4(f2bf(v.x), f2bf(v.y), f2bf(v.z), f2bf(v.w));
    *reinterpret_cast<ushort4*>(&T[r + rr][c4]) = b;
  }
  __syncthreads();
#pragma unroll
  for (int rep = 0; rep < 2; ++rep) {
    int w = t + rep * 256;
    int ml = w >> 3, oct = w & 7;
    uint4 val = *reinterpret_cast<uint4*>(&T[ml][oct * 8]);
    int m = m0 + ml, d = d0 + oct * 8;
    int g = m >> 4, l = m & 15, kk = d >> 5, quad = (d >> 3) & 3;
    *reinterpret_cast<uint4*>(&Kswz[(size_t)(((g * 4 + kk) * 64) + quad * 16 + l) * 8]) = val;
  }
#pragma unroll
  for (int rep = 0; rep < 2; ++rep) {
    int w = t + rep * 256;
    int dl = w >> 3, moct = w & 7;
    unsigned short tmp[8];
#pragma unroll
    for (int j = 0; j < 8; ++j) tmp[j] = T[moct * 8 + j][dl];
    int d = d0 + dl, m = m0 + moct * 8;
    int np = d >> 4, lB = d & 15, mt = m >> 6, mm = m & 63, kk2 = mm >> 5, qB = (mm >> 3) & 3;
    *reinterpret_cast<uint4*>(
        &Vswz[(size_t)((((mt * 8 + np) * 2 + kk2) * 64) + qB * 16 + lB) * 8]) =
        *reinterpret_cast<uint4*>(tmp);
  }
}

// One block: 16 Q-rows x 1024 M-cols. 4 waves split cols. No softmax-max
// rescaling: |logit| <= ~6 so exp() can't overflow; partials add linearly.
//
// Occupancy/latency round: the R5 kernel was latency-bound with everything
// idle (MfmaUtil 4%, VALUBusy 7%, HBM 7%, Occ 25%).
//  - waves_per_eu(5,5): budget >=96 VGPR; measured pressure is 84 at the
//    looser (3,3)/170 budget, so no spills, and 5 resident waves/SIMD
//    (vs 3) to cover the per-iteration L2/HBM dependency chain.
//  - 1D grid of 2048 blocks, XCD-pinned decode: mpart = b&7 follows the
//    HW's round-robin blockIdx->XCD mapping, so each XCD's 4MB L2 holds
//    exactly ONE 512KB Kswz+Vswz column slice, shared by all 256 q-blocks
//    on that XCD. W partitions disjointly (16MB/XCD) and streams through
//    with nt hints so it can't evict the slice. Inner-loop B-frag loads
//    become true L2 hits instead of L3 round-trips.
__global__ __launch_bounds__(256) __attribute__((amdgpu_waves_per_eu(5, 5)))
void attn_kernel(const float* __restrict__ W,
                 const unsigned short* __restrict__ Qs,
                 const unsigned short* __restrict__ Kswz,
                 const unsigned short* __restrict__ Vswz,
                 float* __restrict__ Oacc,
                 float* __restrict__ Lacc) {
  __shared__ __align__(16) unsigned short Plds[NWA][16][72];   // pad 64->72: 16B-aligned b128 reads
  __shared__ float Ored[16][Dn];
  __shared__ float lred[16];

  const int tid  = threadIdx.x;
  const int wave = tid >> 6;
  const int lane = tid & 63;
  const int l    = lane & 15;
  const int quad = lane >> 4;
  const int b    = blockIdx.x;
  const int qb   = (b >> 3) * 16;                  // 256 q-blocks
  const int mbeg = (b & 7) * BCOLS + wave * WCOLS; // XCD-pinned m-slice

  for (int i = tid; i < 16 * Dn; i += 256) ((float*)Ored)[i] = 0.0f;
  if (tid < 16) lred[tid] = 0.0f;
  __syncthreads();

  // Persistent Q A-fragments: A[m=l][k=quad*8+j], kk=0..3 covers D=128.
  bf16x8 aq[4];
  {
    const unsigned short* qrow = Qs + (size_t)(qb + l) * Dn + quad * 8;
#pragma unroll
    for (int kk = 0; kk < 4; ++kk)
      aq[kk] = *reinterpret_cast<const bf16x8*>(qrow + 32 * kk);
  }

  f32x4 O[8];
#pragma unroll
  for (int n = 0; n < 8; ++n) O[n] = (f32x4){0.f, 0.f, 0.f, 0.f};
  float lsum[4] = {0.f, 0.f, 0.f, 0.f};

  // W prefetch: per-lane scalar nt loads at the exact C-layout coordinates
  // the exp step consumes (row=qb+quad*4+r, col=m0+16a+l). Each instruction
  // is 4x64B segments -- line-coalesced. Two banks, distance-1 pipeline.
  float wA[16], wB[16];
#define LOADW(m0_, wr_)                                                          \
  {                                                                              \
    _Pragma("unroll") for (int a4 = 0; a4 < 4; ++a4)                             \
    _Pragma("unroll") for (int r4 = 0; r4 < 4; ++r4)                             \
        (wr_)[a4 * 4 + r4] = __builtin_nontemporal_load(                         \
            &W[(size_t)(qb + quad * 4 + r4) * Mn + (m0_) + 16 * a4 + l]);        \
  }

  LOADW(mbeg, wA);   // W(0)

  // Issue order per iter: Kswz(it) -> W(it+1) -> Vswz(it).
  // PV's wait on Vswz is a fine-grained vmcnt(N) that leaves W(it+1) in
  // flight; W(it+1) drains at S(it+1)'s Kswz wait -- a full iteration of
  // latency slack for the HBM-latency W stream.
#define ITER(it_, WCUR_, WNXT_)                                                  \
  {                                                                              \
    const int m0 = mbeg + (it_) * NT;                                            \
    f32x4 S[4];                                                                  \
    _Pragma("unroll") for (int a = 0; a < 4; ++a)                                \
        S[a] = (f32x4){0.f, 0.f, 0.f, 0.f};                                      \
    _Pragma("unroll") for (int a = 0; a < 4; ++a) {                              \
      _Pragma("unroll") for (int kk = 0; kk < 4; ++kk) {                         \
        bf16x8 bk = *reinterpret_cast<const bf16x8*>(                            \
            Kswz + ((size_t)(((m0 >> 4) + a) * 4 + kk) * 64 + lane) * 8);        \
        S[a] = __builtin_amdgcn_mfma_f32_16x16x32_bf16(aq[kk], bk, S[a], 0, 0, 0);\
      }                                                                          \
    }                                                                            \
    if ((it_) + 1 < NIT) LOADW(m0 + NT, WNXT_);                                  \
    _Pragma("unroll") for (int a = 0; a < 4; ++a) {                              \
      _Pragma("unroll") for (int r = 0; r < 4; ++r) {                            \
        float p = __expf(S[a][r] * (WCUR_)[a * 4 + r]);                          \
        lsum[r] += p;                                                            \
        Plds[wave][quad * 4 + r][16 * a + l] = f2bf(p);                          \
      }                                                                          \
    }                                                                            \
    asm volatile("s_waitcnt lgkmcnt(0)" ::: "memory");                           \
    _Pragma("unroll") for (int kk = 0; kk < 2; ++kk) {                           \
      bf16x8 pa = *reinterpret_cast<const bf16x8*>(                              \
          &Plds[wave][l][32 * kk + quad * 8]);                                   \
      _Pragma("unroll") for (int n = 0; n < 8; ++n) {                            \
        bf16x8 bv = *reinterpret_cast<const bf16x8*>(                            \
            Vswz + ((size_t)(((m0 >> 6) * 8 + n) * 2 + kk) * 64 + lane) * 8);    \
        O[n] = __builtin_amdgcn_mfma_f32_16x16x32_bf16(pa, bv, O[n], 0, 0, 0);   \
      }                                                                          \
    }                                                                            \
  }

  for (int it = 0; it < NIT; it += 2) {
    ITER(it, wA, wB);          // consume W(it) from wA, prefetch W(it+1)->wB
    ITER(it + 1, wB, wA);      // consume from wB, prefetch ->wA
  }
#undef ITER
#undef LOADW

  // Reduce lsum across the 16 lanes of each quad (cols live on l).
#pragma unroll
  for (int r = 0; r < 4; ++r)
#pragma unroll
    for (int off = 1; off < 16; off <<= 1)
      lsum[r] += __shfl_xor(lsum[r], off, 64);

  // Cross-wave combine in LDS (once per kernel; cheap).
#pragma unroll
  for (int n = 0; n < 8; ++n)
#pragma unroll
    for (int r = 0; r < 4; ++r)
      atomicAdd(&Ored[quad * 4 + r][16 * n + l], O[n][r]);
  if (l == 0)
#pragma unroll
    for (int r = 0; r < 4; ++r) atomicAdd(&lred[quad * 4 + r], lsum[r]);
  __syncthreads();

  // Cross-block combine via device atomics (R2/R5-proven footprint).
  for (int i = tid; i < 16 * Dn; i += 256)
    atomicAdd(&Oacc[(size_t)qb * Dn + i], ((float*)Ored)[i]);
  if (tid < 16) atomicAdd(&Lacc[qb + tid], lred[tid]);
}

__global__ void finalize_kernel(const float4* __restrict__ Oacc,
                                const float* __restrict__ Lacc,
                                float4* __restrict__ out) {
  int i = blockIdx.x * blockDim.x + threadIdx.x;   // < Qn*Dn/4
  float4 o = Oacc[i];
  float inv = 1.0f / Lacc[i >> 5];                 // 32 float4 per row
  out[i] = make_float4(o.x * inv, o.y * inv, o.z * inv, o.w * inv);
}

extern "C" void kernel_launch(void* const* d_in, const int* in_sizes, int n_in,
                              void* d_out, int out_size, void* d_ws, size_t ws_size,
                              hipStream_t stream) {
  const float* Q = (const float*)d_in[0];          // [4096,128]
  const float* K = (const float*)d_in[1];          // [8192,128]
  const float* W = (const float*)d_in[2];          // [4096,8192]
  float* out = (float*)d_out;                      // [4096,128]

  unsigned short* Qs   = (unsigned short*)d_ws;               // 1 MB
  unsigned short* Kswz = Qs + (size_t)Qn * Dn;                // 2 MB
  unsigned short* Vswz = Kswz + (size_t)Mn * Dn;              // 2 MB
  float* Oacc = (float*)(Vswz + (size_t)Mn * Dn);             // 2 MB
  float* Lacc = Oacc + (size_t)Qn * Dn;                       // 16 KB (total 7.02 MB)

  int n4 = (Qn * Dn + Qn) / 4;                                // Oacc + Lacc zeroing
  zero_kernel<<<(n4 + 255) / 256, 256, 0, stream>>>((float4*)Oacc, n4);

  cast_q<<<(Qn * Dn / 4) / 256, 256, 0, stream>>>((const float4*)Q, (ushort4*)Qs);
  swz_kernel<<<dim3(Mn / 64, Dn / 64), 256, 0, stream>>>(K, Kswz, Vswz);
  attn_kernel<<<(Qn / 16) * MSPLIT, 256, 0, stream>>>(W, Qs, Kswz, Vswz, Oacc, Lacc);
  finalize_kernel<<<(Qn * Dn / 4) / 256, 256, 0, stream>>>(
      (const float4*)Oacc, Lacc, (float4*)out);
}

// Round 3
// 387.158 us; speedup vs baseline: 1.2593x; 1.2593x over previous
//
#include <hip/hip_runtime.h>
#include <hip/hip_bf16.h>

typedef __attribute__((ext_vector_type(8))) short bf16x8;   // 8 bf16 = 4 VGPRs
typedef __attribute__((ext_vector_type(4))) float f32x4;    // MFMA C/D frag

#define Qn 4096
#define Mn 8192
#define Dn 128
#define NWA 4                    // waves per block
#define MSPLIT 8                 // M split across XCD-pinned block groups
#define BCOLS (Mn / MSPLIT)      // 1024 cols per block
#define WCOLS (BCOLS / NWA)      // 256 cols per wave
#define NT 64                    // cols per iteration
#define NIT (WCOLS / NT)         // 4 iterations per wave

__device__ __forceinline__ unsigned short f2bf(float x) {
  __hip_bfloat16 h = __float2bfloat16(x);
  return *reinterpret_cast<unsigned short*>(&h);
}

__global__ void zero_kernel(float4* __restrict__ p, int n4) {
  int i = blockIdx.x * blockDim.x + threadIdx.x;
  if (i < n4) p[i] = make_float4(0.f, 0.f, 0.f, 0.f);
}

// Q * (1/sqrt(D)) -> bf16, vectorized
__global__ void cast_q(const float4* __restrict__ Q4, ushort4* __restrict__ Qs) {
  int i = blockIdx.x * blockDim.x + threadIdx.x;   // < Qn*Dn/4
  const float s = 0.088388347648318447f;           // 1/sqrt(128)
  float4 q = Q4[i];
  Qs[i] = make_ushort4(f2bf(q.x * s), f2bf(q.y * s), f2bf(q.z * s), f2bf(q.w * s));
}

// Swizzle K into MFMA-fragment-major bf16 layouts so the attn inner loop's
// B-fragment loads are contiguous 1KB per wave instruction (proven R5):
//  Kswz (S=QK^T B-frag):  K[m][d] -> [((m>>4)*4 + (d>>5))*64 + lane][j]
//                         lane = ((d>>3)&3)*16 + (m&15), j = d&7
//  Vswz (PV B-frag, V^T): K[m][d] -> [(((m>>6)*8 + (d>>4))*2 + ((m&63)>>5))*64 + lane][j]
//                         lane = (((m&63)>>3)&3)*16 + (d&15), j = m&7
__global__ __launch_bounds__(256) void swz_kernel(const float* __restrict__ K,
                                                  unsigned short* __restrict__ Kswz,
                                                  unsigned short* __restrict__ Vswz) {
  __shared__ __align__(16) unsigned short T[64][72];   // 64m x 64d tile, bf16, padded
  const int m0 = blockIdx.x * 64, d0 = blockIdx.y * 64;
  const int t = threadIdx.x;
  const int r = t >> 4, c4 = (t & 15) * 4;
#pragma unroll
  for (int rr = 0; rr < 64; rr += 16) {
    float4 v = *reinterpret_cast<const float4*>(&K[(size_t)(m0 + r + rr) * Dn + d0 + c4]);
    ushort4 b = make_ushort4(f2bf(v.x), f2bf(v.y), f2bf(v.z), f2bf(v.w));
    *reinterpret_cast<ushort4*>(&T[r + rr][c4]) = b;
  }
  __syncthreads();
#pragma unroll
  for (int rep = 0; rep < 2; ++rep) {
    int w = t + rep * 256;
    int ml = w >> 3, oct = w & 7;
    uint4 val = *reinterpret_cast<uint4*>(&T[ml][oct * 8]);
    int m = m0 + ml, d = d0 + oct * 8;
    int g = m >> 4, l = m & 15, kk = d >> 5, quad = (d >> 3) & 3;
    *reinterpret_cast<uint4*>(&Kswz[(size_t)(((g * 4 + kk) * 64) + quad * 16 + l) * 8]) = val;
  }
#pragma unroll
  for (int rep = 0; rep < 2; ++rep) {
    int w = t + rep * 256;
    int dl = w >> 3, moct = w & 7;
    unsigned short tmp[8];
#pragma unroll
    for (int j = 0; j < 8; ++j) tmp[j] = T[moct * 8 + j][dl];
    int d = d0 + dl, m = m0 + moct * 8;
    int np = d >> 4, lB = d & 15, mt = m >> 6, mm = m & 63, kk2 = mm >> 5, qB = (mm >> 3) & 3;
    *reinterpret_cast<uint4*>(
        &Vswz[(size_t)((((mt * 8 + np) * 2 + kk2) * 64) + qB * 16 + lB) * 8]) =
        *reinterpret_cast<uint4*>(tmp);
  }
}

// One block: 16 Q-rows x 1024 M-cols. 4 waves split cols. No softmax-max
// rescaling: |logit| <= ~6 so exp() can't overflow; partials add linearly.
//
// VGPR-budget history (critical -- do not retune blindly):
//  - (3,3) [R0]: 84 VGPR, no spill, Occ 25%, attn 167us.
//  - (5,5) [R1]: allocator squeezed to 48 VGPR, spilled wA/wB/O to scratch:
//    WRITE_SIZE 8MB->345MB, attn 338us. (5,5)'s ~96-VGPR budget is BELOW
//    the ~84-VGPR live set once allocator overhead is counted. NEVER (5,5).
//  - (4,4) [this round]: 128-VGPR budget >= 84 live, 4 waves/SIMD (50% occ).
//
// 1D grid of 2048 blocks, XCD-pinned decode: mpart = b&7 follows the HW's
// round-robin blockIdx->XCD mapping, so each XCD's 4MB L2 holds exactly ONE
// 512KB Kswz+Vswz column slice, shared by all 256 q-blocks on that XCD.
// W partitions disjointly (16MB/XCD) and streams through with nt hints so
// it can't evict the slice.
__global__ __launch_bounds__(256) __attribute__((amdgpu_waves_per_eu(4, 4)))
void attn_kernel(const float* __restrict__ W,
                 const unsigned short* __restrict__ Qs,
                 const unsigned short* __restrict__ Kswz,
                 const unsigned short* __restrict__ Vswz,
                 float* __restrict__ Oacc,
                 float* __restrict__ Lacc) {
  __shared__ __align__(16) unsigned short Plds[NWA][16][72];   // pad 64->72: 16B-aligned b128 reads
  __shared__ float Ored[16][Dn];
  __shared__ float lred[16];

  const int tid  = threadIdx.x;
  const int wave = tid >> 6;
  const int lane = tid & 63;
  const int l    = lane & 15;
  const int quad = lane >> 4;
  const int b    = blockIdx.x;
  const int qb   = (b >> 3) * 16;                  // 256 q-blocks
  const int mbeg = (b & 7) * BCOLS + wave * WCOLS; // XCD-pinned m-slice

  for (int i = tid; i < 16 * Dn; i += 256) ((float*)Ored)[i] = 0.0f;
  if (tid < 16) lred[tid] = 0.0f;
  __syncthreads();

  // Persistent Q A-fragments: A[m=l][k=quad*8+j], kk=0..3 covers D=128.
  bf16x8 aq[4];
  {
    const unsigned short* qrow = Qs + (size_t)(qb + l) * Dn + quad * 8;
#pragma unroll
    for (int kk = 0; kk < 4; ++kk)
      aq[kk] = *reinterpret_cast<const bf16x8*>(qrow + 32 * kk);
  }

  f32x4 O[8];
#pragma unroll
  for (int n = 0; n < 8; ++n) O[n] = (f32x4){0.f, 0.f, 0.f, 0.f};
  float lsum[4] = {0.f, 0.f, 0.f, 0.f};

  // W prefetch: per-lane scalar nt loads at the exact C-layout coordinates
  // the exp step consumes (row=qb+quad*4+r, col=m0+16a+l). Each instruction
  // is 4x64B segments -- line-coalesced. Two banks, distance-1 pipeline.
  float wA[16], wB[16];
#define LOADW(m0_, wr_)                                                          \
  {                                                                              \
    _Pragma("unroll") for (int a4 = 0; a4 < 4; ++a4)                             \
    _Pragma("unroll") for (int r4 = 0; r4 < 4; ++r4)                             \
        (wr_)[a4 * 4 + r4] = __builtin_nontemporal_load(                         \
            &W[(size_t)(qb + quad * 4 + r4) * Mn + (m0_) + 16 * a4 + l]);        \
  }

  LOADW(mbeg, wA);   // W(0)

  // Issue order per iter: Kswz(it) -> W(it+1) -> Vswz(it).
  // PV's wait on Vswz is a fine-grained vmcnt(N) that leaves W(it+1) in
  // flight; W(it+1) drains at S(it+1)'s Kswz wait -- a full iteration of
  // latency slack for the HBM-latency W stream.
#define ITER(it_, WCUR_, WNXT_)                                                  \
  {                                                                              \
    const int m0 = mbeg + (it_) * NT;                                            \
    f32x4 S[4];                                                                  \
    _Pragma("unroll") for (int a = 0; a < 4; ++a)                                \
        S[a] = (f32x4){0.f, 0.f, 0.f, 0.f};                                      \
    _Pragma("unroll") for (int a = 0; a < 4; ++a) {                              \
      _Pragma("unroll") for (int kk = 0; kk < 4; ++kk) {                         \
        bf16x8 bk = *reinterpret_cast<const bf16x8*>(                            \
            Kswz + ((size_t)(((m0 >> 4) + a) * 4 + kk) * 64 + lane) * 8);        \
        S[a] = __builtin_amdgcn_mfma_f32_16x16x32_bf16(aq[kk], bk, S[a], 0, 0, 0);\
      }                                                                          \
    }                                                                            \
    if ((it_) + 1 < NIT) LOADW(m0 + NT, WNXT_);                                  \
    _Pragma("unroll") for (int a = 0; a < 4; ++a) {                              \
      _Pragma("unroll") for (int r = 0; r < 4; ++r) {                            \
        float p = __expf(S[a][r] * (WCUR_)[a * 4 + r]);                          \
        lsum[r] += p;                                                            \
        Plds[wave][quad * 4 + r][16 * a + l] = f2bf(p);                          \
      }                                                                          \
    }                                                                            \
    asm volatile("s_waitcnt lgkmcnt(0)" ::: "memory");                           \
    _Pragma("unroll") for (int kk = 0; kk < 2; ++kk) {                           \
      bf16x8 pa = *reinterpret_cast<const bf16x8*>(                              \
          &Plds[wave][l][32 * kk + quad * 8]);                                   \
      _Pragma("unroll") for (int n = 0; n < 8; ++n) {                            \
        bf16x8 bv = *reinterpret_cast<const bf16x8*>(                            \
            Vswz + ((size_t)(((m0 >> 6) * 8 + n) * 2 + kk) * 64 + lane) * 8);    \
        O[n] = __builtin_amdgcn_mfma_f32_16x16x32_bf16(pa, bv, O[n], 0, 0, 0);   \
      }                                                                          \
    }                                                                            \
  }

  for (int it = 0; it < NIT; it += 2) {
    ITER(it, wA, wB);          // consume W(it) from wA, prefetch W(it+1)->wB
    ITER(it + 1, wB, wA);      // consume from wB, prefetch ->wA
  }
#undef ITER
#undef LOADW

  // Reduce lsum across the 16 lanes of each quad (cols live on l).
#pragma unroll
  for (int r = 0; r < 4; ++r)
#pragma unroll
    for (int off = 1; off < 16; off <<= 1)
      lsum[r] += __shfl_xor(lsum[r], off, 64);

  // Cross-wave combine in LDS (once per kernel; cheap).
#pragma unroll
  for (int n = 0; n < 8; ++n)
#pragma unroll
    for (int r = 0; r < 4; ++r)
      atomicAdd(&Ored[quad * 4 + r][16 * n + l], O[n][r]);
  if (l == 0)
#pragma unroll
    for (int r = 0; r < 4; ++r) atomicAdd(&lred[quad * 4 + r], lsum[r]);
  __syncthreads();

  // Cross-block combine via device atomics (R2/R5-proven footprint).
  for (int i = tid; i < 16 * Dn; i += 256)
    atomicAdd(&Oacc[(size_t)qb * Dn + i], ((float*)Ored)[i]);
  if (tid < 16) atomicAdd(&Lacc[qb + tid], lred[tid]);
}

__global__ void finalize_kernel(const float4* __restrict__ Oacc,
                                const float* __restrict__ Lacc,
                                float4* __restrict__ out) {
  int i = blockIdx.x * blockDim.x + threadIdx.x;   // < Qn*Dn/4
  float4 o = Oacc[i];
  float inv = 1.0f / Lacc[i >> 5];                 // 32 float4 per row
  out[i] = make_float4(o.x * inv, o.y * inv, o.z * inv, o.w * inv);
}

extern "C" void kernel_launch(void* const* d_in, const int* in_sizes, int n_in,
                              void* d_out, int out_size, void* d_ws, size_t ws_size,
                              hipStream_t stream) {
  const float* Q = (const float*)d_in[0];          // [4096,128]
  const float* K = (const float*)d_in[1];          // [8192,128]
  const float* W = (const float*)d_in[2];          // [4096,8192]
  float* out = (float*)d_out;                      // [4096,128]

  unsigned short* Qs   = (unsigned short*)d_ws;               // 1 MB
  unsigned short* Kswz = Qs + (size_t)Qn * Dn;                // 2 MB
  unsigned short* Vswz = Kswz + (size_t)Mn * Dn;              // 2 MB
  float* Oacc = (float*)(Vswz + (size_t)Mn * Dn);             // 2 MB
  float* Lacc = Oacc + (size_t)Qn * Dn;                       // 16 KB (total 7.02 MB)

  int n4 = (Qn * Dn + Qn) / 4;                                // Oacc + Lacc zeroing
  zero_kernel<<<(n4 + 255) / 256, 256, 0, stream>>>((float4*)Oacc, n4);

  cast_q<<<(Qn * Dn / 4) / 256, 256, 0, stream>>>((const float4*)Q, (ushort4*)Qs);
  swz_kernel<<<dim3(Mn / 64, Dn / 64), 256, 0, stream>>>(K, Kswz, Vswz);
  attn_kernel<<<(Qn / 16) * MSPLIT, 256, 0, stream>>>(W, Qs, Kswz, Vswz, Oacc, Lacc);
  finalize_kernel<<<(Qn * Dn / 4) / 256, 256, 0, stream>>>(
      (const float4*)Oacc, Lacc, (float4*)out);
}

// Round 4
// 328.294 us; speedup vs baseline: 1.4851x; 1.1793x over previous
//
#include <hip/hip_runtime.h>
#include <hip/hip_bf16.h>

typedef __attribute__((ext_vector_type(8))) short bf16x8;   // 8 bf16 = 4 VGPRs
typedef __attribute__((ext_vector_type(4))) float f32x4;    // MFMA C/D frag

#define Qn 4096
#define Mn 8192
#define Dn 128
#define NWA 4                    // waves per block
#define MSPLIT 8                 // M split across XCD-pinned block groups
#define BCOLS (Mn / MSPLIT)      // 1024 cols per block
#define WCOLS (BCOLS / NWA)      // 256 cols per wave
#define NT 64                    // cols per iteration
#define NIT (WCOLS / NT)         // 4 iterations per wave

__device__ __forceinline__ unsigned short f2bf(float x) {
  __hip_bfloat16 h = __float2bfloat16(x);
  return *reinterpret_cast<unsigned short*>(&h);
}

__global__ void zero_kernel(float4* __restrict__ p, int n4) {
  int i = blockIdx.x * blockDim.x + threadIdx.x;
  if (i < n4) p[i] = make_float4(0.f, 0.f, 0.f, 0.f);
}

// Q * (1/sqrt(D)) -> bf16, vectorized
__global__ void cast_q(const float4* __restrict__ Q4, ushort4* __restrict__ Qs) {
  int i = blockIdx.x * blockDim.x + threadIdx.x;   // < Qn*Dn/4
  const float s = 0.088388347648318447f;           // 1/sqrt(128)
  float4 q = Q4[i];
  Qs[i] = make_ushort4(f2bf(q.x * s), f2bf(q.y * s), f2bf(q.z * s), f2bf(q.w * s));
}

// Swizzle K into MFMA-fragment-major bf16 layouts so the attn inner loop's
// B-fragment loads are contiguous 1KB per wave instruction (proven R5):
//  Kswz (S=QK^T B-frag):  K[m][d] -> [((m>>4)*4 + (d>>5))*64 + lane][j]
//                         lane = ((d>>3)&3)*16 + (m&15), j = d&7
//  Vswz (PV B-frag, V^T): K[m][d] -> [(((m>>6)*8 + (d>>4))*2 + ((m&63)>>5))*64 + lane][j]
//                         lane = (((m&63)>>3)&3)*16 + (d&15), j = m&7
__global__ __launch_bounds__(256) void swz_kernel(const float* __restrict__ K,
                                                  unsigned short* __restrict__ Kswz,
                                                  unsigned short* __restrict__ Vswz) {
  __shared__ __align__(16) unsigned short T[64][72];   // 64m x 64d tile, bf16, padded
  const int m0 = blockIdx.x * 64, d0 = blockIdx.y * 64;
  const int t = threadIdx.x;
  const int r = t >> 4, c4 = (t & 15) * 4;
#pragma unroll
  for (int rr = 0; rr < 64; rr += 16) {
    float4 v = *reinterpret_cast<const float4*>(&K[(size_t)(m0 + r + rr) * Dn + d0 + c4]);
    ushort4 b = make_ushort4(f2bf(v.x), f2bf(v.y), f2bf(v.z), f2bf(v.w));
    *reinterpret_cast<ushort4*>(&T[r + rr][c4]) = b;
  }
  __syncthreads();
#pragma unroll
  for (int rep = 0; rep < 2; ++rep) {
    int w = t + rep * 256;
    int ml = w >> 3, oct = w & 7;
    uint4 val = *reinterpret_cast<uint4*>(&T[ml][oct * 8]);
    int m = m0 + ml, d = d0 + oct * 8;
    int g = m >> 4, l = m & 15, kk = d >> 5, quad = (d >> 3) & 3;
    *reinterpret_cast<uint4*>(&Kswz[(size_t)(((g * 4 + kk) * 64) + quad * 16 + l) * 8]) = val;
  }
#pragma unroll
  for (int rep = 0; rep < 2; ++rep) {
    int w = t + rep * 256;
    int dl = w >> 3, moct = w & 7;
    unsigned short tmp[8];
#pragma unroll
    for (int j = 0; j < 8; ++j) tmp[j] = T[moct * 8 + j][dl];
    int d = d0 + dl, m = m0 + moct * 8;
    int np = d >> 4, lB = d & 15, mt = m >> 6, mm = m & 63, kk2 = mm >> 5, qB = (mm >> 3) & 3;
    *reinterpret_cast<uint4*>(
        &Vswz[(size_t)((((mt * 8 + np) * 2 + kk2) * 64) + qB * 16 + lB) * 8]) =
        *reinterpret_cast<uint4*>(tmp);
  }
}

// One block: 16 Q-rows x 1024 M-cols. 4 waves split cols. No softmax-max
// rescaling: |logit| <= ~6 so exp() can't overflow; partials add linearly.
//
// VGPR-budget law (measured R0/R1/R3 -- do not retune):
//  - (3,3): 84 VGPR, no spill, 167us.            <- ONLY safe pin
//  - (4,4): alloc 64, spilled ~210MB scratch, 225us.
//  - (5,5): alloc 48, spilled ~550MB scratch, 338us.
//  Live set ~150-170 regs (unified VGPR+acc file) -> any pin >=4 waves/SIMD
//  forces <=128-reg budget -> scratch. Occupancy lever is CLOSED; latency
//  must be hidden inside the wave (register pipelining below).
//
// R4 change: V-load pipeline. The lgkmcnt asm is a full compiler memory
// barrier; previously all 16 Vswz loads sat AFTER it -> ~200-500cy exposed
// L2 latency per iter. Now bv0 is issued right after QK (covered by
// exp+LDS-write), bv1 after the LDS writes (covered by lgkm wait + pa reads
// + kk0 MFMAs). LOADW(next) issues AFTER bv1 so PV's in-order vmcnt wait on
// bv1 never drains the long-latency W stream; W drains during next iter's
// K-load wait instead (full PV+QK window of slack).
__global__ __launch_bounds__(256) __attribute__((amdgpu_waves_per_eu(3, 3)))
void attn_kernel(const float* __restrict__ W,
                 const unsigned short* __restrict__ Qs,
                 const unsigned short* __restrict__ Kswz,
                 const unsigned short* __restrict__ Vswz,
                 float* __restrict__ Oacc,
                 float* __restrict__ Lacc) {
  __shared__ __align__(16) unsigned short Plds[NWA][16][72];   // pad 64->72: 16B-aligned b128 reads
  __shared__ float Ored[16][Dn];
  __shared__ float lred[16];

  const int tid  = threadIdx.x;
  const int wave = tid >> 6;
  const int lane = tid & 63;
  const int l    = lane & 15;
  const int quad = lane >> 4;
  const int b    = blockIdx.x;
  const int qb   = (b >> 3) * 16;                  // 256 q-blocks
  const int mbeg = (b & 7) * BCOLS + wave * WCOLS; // XCD-pinned m-slice

  for (int i = tid; i < 16 * Dn; i += 256) ((float*)Ored)[i] = 0.0f;
  if (tid < 16) lred[tid] = 0.0f;
  __syncthreads();

  // Persistent Q A-fragments: A[m=l][k=quad*8+j], kk=0..3 covers D=128.
  bf16x8 aq[4];
  {
    const unsigned short* qrow = Qs + (size_t)(qb + l) * Dn + quad * 8;
#pragma unroll
    for (int kk = 0; kk < 4; ++kk)
      aq[kk] = *reinterpret_cast<const bf16x8*>(qrow + 32 * kk);
  }

  f32x4 O[8];
#pragma unroll
  for (int n = 0; n < 8; ++n) O[n] = (f32x4){0.f, 0.f, 0.f, 0.f};
  float lsum[4] = {0.f, 0.f, 0.f, 0.f};

  // W prefetch: per-lane scalar nt loads at the exact C-layout coordinates
  // the exp step consumes (row=qb+quad*4+r, col=m0+16a+l). Each instruction
  // is 4x64B segments -- line-coalesced. Two banks, distance-1 pipeline.
  float wA[16], wB[16];
#define LOADW(m0_, wr_)                                                          \
  {                                                                              \
    _Pragma("unroll") for (int a4 = 0; a4 < 4; ++a4)                             \
    _Pragma("unroll") for (int r4 = 0; r4 < 4; ++r4)                             \
        (wr_)[a4 * 4 + r4] = __builtin_nontemporal_load(                         \
            &W[(size_t)(qb + quad * 4 + r4) * Mn + (m0_) + 16 * a4 + l]);        \
  }

  LOADW(mbeg, wA);   // W(0)

#define ITER(it_, WCUR_, WNXT_)                                                  \
  {                                                                              \
    const int m0 = mbeg + (it_) * NT;                                            \
    f32x4 S[4];                                                                  \
    _Pragma("unroll") for (int a = 0; a < 4; ++a)                                \
        S[a] = (f32x4){0.f, 0.f, 0.f, 0.f};                                      \
    _Pragma("unroll") for (int a = 0; a < 4; ++a) {                              \
      _Pragma("unroll") for (int kk = 0; kk < 4; ++kk) {                         \
        bf16x8 bk = *reinterpret_cast<const bf16x8*>(                            \
            Kswz + ((size_t)(((m0 >> 4) + a) * 4 + kk) * 64 + lane) * 8);        \
        S[a] = __builtin_amdgcn_mfma_f32_16x16x32_bf16(aq[kk], bk, S[a], 0, 0, 0);\
      }                                                                          \
    }                                                                            \
    /* V pipeline, half 1: issue now, consume after the barrier. */              \
    bf16x8 bv0[8];                                                               \
    _Pragma("unroll") for (int n = 0; n < 8; ++n)                                \
      bv0[n] = *reinterpret_cast<const bf16x8*>(                                 \
          Vswz + ((size_t)(((m0 >> 6) * 8 + n) * 2 + 0) * 64 + lane) * 8);       \
    _Pragma("unroll") for (int a = 0; a < 4; ++a) {                              \
      _Pragma("unroll") for (int r = 0; r < 4; ++r) {                            \
        float p = __expf(S[a][r] * (WCUR_)[a * 4 + r]);                          \
        lsum[r] += p;                                                            \
        Plds[wave][quad * 4 + r][16 * a + l] = f2bf(p);                          \
      }                                                                          \
    }                                                                            \
    /* V pipeline, half 2 (reuses S's dead registers). */                        \
    bf16x8 bv1[8];                                                               \
    _Pragma("unroll") for (int n = 0; n < 8; ++n)                                \
      bv1[n] = *reinterpret_cast<const bf16x8*>(                                 \
          Vswz + ((size_t)(((m0 >> 6) * 8 + n) * 2 + 1) * 64 + lane) * 8);       \
    /* W AFTER bv1: PV's vmcnt wait on bv1 must not drain the W stream. */       \
    if ((it_) + 1 < NIT) LOADW(m0 + NT, WNXT_);                                  \
    asm volatile("s_waitcnt lgkmcnt(0)" ::: "memory");                           \
    bf16x8 pa0 = *reinterpret_cast<const bf16x8*>(&Plds[wave][l][quad * 8]);     \
    bf16x8 pa1 = *reinterpret_cast<const bf16x8*>(&Plds[wave][l][32 + quad * 8]);\
    _Pragma("unroll") for (int n = 0; n < 8; ++n)                                \
      O[n] = __builtin_amdgcn_mfma_f32_16x16x32_bf16(pa0, bv0[n], O[n], 0, 0, 0);\
    _Pragma("unroll") for (int n = 0; n < 8; ++n)                                \
      O[n] = __builtin_amdgcn_mfma_f32_16x16x32_bf16(pa1, bv1[n], O[n], 0, 0, 0);\
  }

  for (int it = 0; it < NIT; it += 2) {
    ITER(it, wA, wB);          // consume W(it) from wA, prefetch W(it+1)->wB
    ITER(it + 1, wB, wA);      // consume from wB, prefetch ->wA
  }
#undef ITER
#undef LOADW

  // Reduce lsum across the 16 lanes of each quad (cols live on l).
#pragma unroll
  for (int r = 0; r < 4; ++r)
#pragma unroll
    for (int off = 1; off < 16; off <<= 1)
      lsum[r] += __shfl_xor(lsum[r], off, 64);

  // Cross-wave combine in LDS (once per kernel; cheap).
#pragma unroll
  for (int n = 0; n < 8; ++n)
#pragma unroll
    for (int r = 0; r < 4; ++r)
      atomicAdd(&Ored[quad * 4 + r][16 * n + l], O[n][r]);
  if (l == 0)
#pragma unroll
    for (int r = 0; r < 4; ++r) atomicAdd(&lred[quad * 4 + r], lsum[r]);
  __syncthreads();

  // Cross-block combine via device atomics (R2/R5-proven footprint).
  for (int i = tid; i < 16 * Dn; i += 256)
    atomicAdd(&Oacc[(size_t)qb * Dn + i], ((float*)Ored)[i]);
  if (tid < 16) atomicAdd(&Lacc[qb + tid], lred[tid]);
}

__global__ void finalize_kernel(const float4* __restrict__ Oacc,
                                const float* __restrict__ Lacc,
                                float4* __restrict__ out) {
  int i = blockIdx.x * blockDim.x + threadIdx.x;   // < Qn*Dn/4
  float4 o = Oacc[i];
  float inv = 1.0f / Lacc[i >> 5];                 // 32 float4 per row
  out[i] = make_float4(o.x * inv, o.y * inv, o.z * inv, o.w * inv);
}

extern "C" void kernel_launch(void* const* d_in, const int* in_sizes, int n_in,
                              void* d_out, int out_size, void* d_ws, size_t ws_size,
                              hipStream_t stream) {
  const float* Q = (const float*)d_in[0];          // [4096,128]
  const float* K = (const float*)d_in[1];          // [8192,128]
  const float* W = (const float*)d_in[2];          // [4096,8192]
  float* out = (float*)d_out;                      // [4096,128]

  unsigned short* Qs   = (unsigned short*)d_ws;               // 1 MB
  unsigned short* Kswz = Qs + (size_t)Qn * Dn;                // 2 MB
  unsigned short* Vswz = Kswz + (size_t)Mn * Dn;              // 2 MB
  float* Oacc = (float*)(Vswz + (size_t)Mn * Dn);             // 2 MB
  float* Lacc = Oacc + (size_t)Qn * Dn;                       // 16 KB (total 7.02 MB)

  int n4 = (Qn * Dn + Qn) / 4;                                // Oacc + Lacc zeroing
  zero_kernel<<<(n4 + 255) / 256, 256, 0, stream>>>((float4*)Oacc, n4);

  cast_q<<<(Qn * Dn / 4) / 256, 256, 0, stream>>>((const float4*)Q, (ushort4*)Qs);
  swz_kernel<<<dim3(Mn / 64, Dn / 64), 256, 0, stream>>>(K, Kswz, Vswz);
  attn_kernel<<<(Qn / 16) * MSPLIT, 256, 0, stream>>>(W, Qs, Kswz, Vswz, Oacc, Lacc);
  finalize_kernel<<<(Qn * Dn / 4) / 256, 256, 0, stream>>>(
      (const float4*)Oacc, Lacc, (float4*)out);
}

// Round 5
// 225.564 us; speedup vs baseline: 2.1615x; 1.4554x over previous
//
#include <hip/hip_runtime.h>
#include <hip/hip_bf16.h>

typedef __attribute__((ext_vector_type(8))) short bf16x8;   // 8 bf16 = 4 VGPRs
typedef __attribute__((ext_vector_type(4))) float f32x4;    // MFMA C/D frag

#define Qn 4096
#define Mn 8192
#define Dn 128
#define NWA 4                    // waves per block
#define QB 64                    // q-rows per block (16 per wave)
#define MSPLIT 8                 // M split across XCD-pinned block groups
#define BCOLS (Mn / MSPLIT)      // 1024 cols per block
#define TILE 64                  // m-cols per staged tile
#define NIT (BCOLS / TILE)       // 16 iterations per block

__device__ __forceinline__ unsigned short f2bf(float x) {
  __hip_bfloat16 h = __float2bfloat16(x);
  return *reinterpret_cast<unsigned short*>(&h);
}

// Async global->LDS, 16B per lane. LDS dest is WAVE-UNIFORM base (HW adds
// lane*16); global src is per-lane.
__device__ __forceinline__ void gld_lds16(const void* g, void* l) {
  __builtin_amdgcn_global_load_lds(
      (const __attribute__((address_space(1))) unsigned int*)g,
      (__attribute__((address_space(3))) unsigned int*)l, 16, 0, 0);
}

__global__ void zero_kernel(float4* __restrict__ p, int n4) {
  int i = blockIdx.x * blockDim.x + threadIdx.x;
  if (i < n4) p[i] = make_float4(0.f, 0.f, 0.f, 0.f);
}

// Q * (1/sqrt(D)) -> bf16, vectorized
__global__ void cast_q(const float4* __restrict__ Q4, ushort4* __restrict__ Qs) {
  int i = blockIdx.x * blockDim.x + threadIdx.x;   // < Qn*Dn/4
  const float s = 0.088388347648318447f;           // 1/sqrt(128)
  float4 q = Q4[i];
  Qs[i] = make_ushort4(f2bf(q.x * s), f2bf(q.y * s), f2bf(q.z * s), f2bf(q.w * s));
}

// Swizzle K into MFMA-fragment-major bf16 layouts (proven R5). Key property
// used by the new attn kernel: a 64-col tile at 64-aligned m0 is a CONTIGUOUS
// 16KB region at byte offset m0*256 in both arrays, so it can be staged into
// LDS linearly and fragment reads use the same in-tile offsets:
//  Kswz in-tile frag: ((a*4+kk)*64 + lane)*8 shorts  (a = m-subtile 0..3)
//  Vswz in-tile frag: ((n*2+kk)*64 + lane)*8 shorts  (n = d-subtile 0..7)
__global__ __launch_bounds__(256) void swz_kernel(const float* __restrict__ K,
                                                  unsigned short* __restrict__ Kswz,
                                                  unsigned short* __restrict__ Vswz) {
  __shared__ __align__(16) unsigned short T[64][72];   // 64m x 64d tile, bf16, padded
  const int m0 = blockIdx.x * 64, d0 = blockIdx.y * 64;
  const int t = threadIdx.x;
  const int r = t >> 4, c4 = (t & 15) * 4;
#pragma unroll
  for (int rr = 0; rr < 64; rr += 16) {
    float4 v = *reinterpret_cast<const float4*>(&K[(size_t)(m0 + r + rr) * Dn + d0 + c4]);
    ushort4 b = make_ushort4(f2bf(v.x), f2bf(v.y), f2bf(v.z), f2bf(v.w));
    *reinterpret_cast<ushort4*>(&T[r + rr][c4]) = b;
  }
  __syncthreads();
#pragma unroll
  for (int rep = 0; rep < 2; ++rep) {
    int w = t + rep * 256;
    int ml = w >> 3, oct = w & 7;
    uint4 val = *reinterpret_cast<uint4*>(&T[ml][oct * 8]);
    int m = m0 + ml, d = d0 + oct * 8;
    int g = m >> 4, l = m & 15, kk = d >> 5, quad = (d >> 3) & 3;
    *reinterpret_cast<uint4*>(&Kswz[(size_t)(((g * 4 + kk) * 64) + quad * 16 + l) * 8]) = val;
  }
#pragma unroll
  for (int rep = 0; rep < 2; ++rep) {
    int w = t + rep * 256;
    int dl = w >> 3, moct = w & 7;
    unsigned short tmp[8];
#pragma unroll
    for (int j = 0; j < 8; ++j) tmp[j] = T[moct * 8 + j][dl];
    int d = d0 + dl, m = m0 + moct * 8;
    int np = d >> 4, lB = d & 15, mt = m >> 6, mm = m & 63, kk2 = mm >> 5, qB = (mm >> 3) & 3;
    *reinterpret_cast<uint4*>(
        &Vswz[(size_t)((((mt * 8 + np) * 2 + kk2) * 64) + qB * 16 + lB) * 8]) =
        *reinterpret_cast<uint4*>(tmp);
  }
}

// R5 restructure, driven by the measured law: wall cycles/CU == VMEM
// lane-requests/CU at ~1 lane/cycle (R0/R1/R3/R4 all match within 5%).
// Old: every wave re-read K/V frags + 16 scalar W per iter = 48 VMEM
// instr/wave/iter -> 393K lane-cy/CU -> 164us, insensitive to occupancy
// and issue order. New: block = 64q x 1024m, 4 waves SPLIT Q and SHARE
// each 64-col K/V tile staged once into LDS via global_load_lds (16B,
// contiguous Kswz/Vswz chunks -> in-tile ds_read offsets identical to the
// old global fragment math). W staged 16B/lane coalesced into LDS too.
// 12 VMEM instr/wave/iter -> ~98K lane-cy/CU -> predicts ~50-70us.
//
// W LDS swizzle: read pattern [quad*4+r][16a+l] is 4-way bank-aliased
// (bank=col%32, rows collide). Store col' = col ^ ((row>>2)*16) by
// pre-XORing the SOURCE col (global_load_lds dest must stay linear);
// read with the same XOR -> 2-way (free, m136).
//
// VGPR history: (5,5)/(4,4) spill (R1/R3). Live set here is smaller (no
// wA/wB, no bv regs): (2,2) = 256-reg budget, supply is 2 blocks/CU anyway.
__global__ __launch_bounds__(256) __attribute__((amdgpu_waves_per_eu(2, 2)))
void attn_kernel(const float* __restrict__ W,
                 const unsigned short* __restrict__ Qs,
                 const unsigned short* __restrict__ Kswz,
                 const unsigned short* __restrict__ Vswz,
                 float* __restrict__ Oacc,
                 float* __restrict__ Lacc) {
  __shared__ __align__(16) unsigned short Klds[16 * 64 * 8];   // 16KB K tile
  __shared__ __align__(16) unsigned short Vlds[16 * 64 * 8];   // 16KB V tile
  __shared__ __align__(16) float Wlds[NWA][16][64];            // 16KB W tile
  __shared__ __align__(16) unsigned short Plds[NWA][16][72];   // 9.2KB P

  const int tid  = threadIdx.x;
  const int wave = tid >> 6;
  const int lane = tid & 63;
  const int l    = lane & 15;
  const int quad = lane >> 4;
  const int b    = blockIdx.x;
  const int qb   = (b >> 3) * QB;      // 64 q-blocks
  const int mbeg = (b & 7) * BCOLS;    // XCD-pinned m-slice
  const int qw   = qb + wave * 16;     // this wave's q-row base

  // Persistent Q A-fragments for this wave's 16 rows.
  bf16x8 aq[4];
  {
    const unsigned short* qrow = Qs + (size_t)(qw + l) * Dn + quad * 8;
#pragma unroll
    for (int kk = 0; kk < 4; ++kk)
      aq[kk] = *reinterpret_cast<const bf16x8*>(qrow + 32 * kk);
  }

  f32x4 O[8];
#pragma unroll
  for (int n = 0; n < 8; ++n) O[n] = (f32x4){0.f, 0.f, 0.f, 0.f};
  float lsum[4] = {0.f, 0.f, 0.f, 0.f};

  for (int it = 0; it < NIT; ++it) {
    const int m0 = mbeg + it * TILE;
    __syncthreads();   // prev tile's LDS reads done before overwrite

    // Stage K/V tiles: 16KB each, contiguous at byte offset m0*256.
    {
      const unsigned short* ksrc = Kswz + (size_t)m0 * 128;
      const unsigned short* vsrc = Vswz + (size_t)m0 * 128;
#pragma unroll
      for (int i = 0; i < 4; ++i) {
        const int c = wave * 4 + i;                 // 1KB chunk 0..15
        gld_lds16(ksrc + (size_t)c * 512 + lane * 8, &Klds[c * 512]);
        gld_lds16(vsrc + (size_t)c * 512 + lane * 8, &Vlds[c * 512]);
      }
    }
    // Stage this wave's W tile: 16 rows x 64 cols fp32, row-major with
    // col pre-XOR (see header comment). Lane covers row i*4+(lane>>4),
    // cols ((lane&15)*4) ^ (i*16) .. +3 (XOR preserves the float4).
#pragma unroll
    for (int i = 0; i < 4; ++i) {
      const float* wsrc = &W[(size_t)(qw + i * 4 + (lane >> 4)) * Mn + m0 +
                             (((lane & 15) * 4) ^ (i * 16))];
      gld_lds16(wsrc, &Wlds[wave][i * 4][0]);
    }
    __syncthreads();   // vmcnt(0) drain + barrier: tiles ready

    // QK^T: S[a] = Q(16q x 128) . K^T for m-subtile a (16 cols each).
    f32x4 S[4];
#pragma unroll
    for (int a = 0; a < 4; ++a) S[a] = (f32x4){0.f, 0.f, 0.f, 0.f};
#pragma unroll
    for (int a = 0; a < 4; ++a)
#pragma unroll
      for (int kk = 0; kk < 4; ++kk) {
        bf16x8 bk = *reinterpret_cast<const bf16x8*>(
            &Klds[((a * 4 + kk) * 64 + lane) * 8]);
        S[a] = __builtin_amdgcn_mfma_f32_16x16x32_bf16(aq[kk], bk, S[a], 0, 0, 0);
      }

    // P = exp(S*W); stash bf16 P in LDS for the lane transpose.
#pragma unroll
    for (int a = 0; a < 4; ++a)
#pragma unroll
      for (int r = 0; r < 4; ++r) {
        float wv = Wlds[wave][quad * 4 + r][(16 * a + l) ^ (quad * 16)];
        float p = __expf(S[a][r] * wv);
        lsum[r] += p;
        Plds[wave][quad * 4 + r][16 * a + l] = f2bf(p);
      }
    asm volatile("s_waitcnt lgkmcnt(0)" ::: "memory");

    // PV: O += P(16q x 64m) . V(64m x 128d)
#pragma unroll
    for (int kk = 0; kk < 2; ++kk) {
      bf16x8 pa = *reinterpret_cast<const bf16x8*>(
          &Plds[wave][l][32 * kk + quad * 8]);
#pragma unroll
      for (int n = 0; n < 8; ++n) {
        bf16x8 bv = *reinterpret_cast<const bf16x8*>(
            &Vlds[((n * 2 + kk) * 64 + lane) * 8]);
        O[n] = __builtin_amdgcn_mfma_f32_16x16x32_bf16(pa, bv, O[n], 0, 0, 0);
      }
    }
  }

  // lsum reduce across the 16 l-lanes of each quad (m-cols live on l).
#pragma unroll
  for (int r = 0; r < 4; ++r)
#pragma unroll
    for (int off = 1; off < 16; off <<= 1)
      lsum[r] += __shfl_xor(lsum[r], off, 64);

  // Waves own distinct q-rows: no cross-wave combine needed. Cross-block
  // (MSPLIT) combine via device atomics.
#pragma unroll
  for (int n = 0; n < 8; ++n)
#pragma unroll
    for (int r = 0; r < 4; ++r)
      atomicAdd(&Oacc[(size_t)(qw + quad * 4 + r) * Dn + 16 * n + l], O[n][r]);
  if (l == 0)
#pragma unroll
    for (int r = 0; r < 4; ++r) atomicAdd(&Lacc[qw + quad * 4 + r], lsum[r]);
}

__global__ void finalize_kernel(const float4* __restrict__ Oacc,
                                const float* __restrict__ Lacc,
                                float4* __restrict__ out) {
  int i = blockIdx.x * blockDim.x + threadIdx.x;   // < Qn*Dn/4
  float4 o = Oacc[i];
  float inv = 1.0f / Lacc[i >> 5];                 // 32 float4 per row
  out[i] = make_float4(o.x * inv, o.y * inv, o.z * inv, o.w * inv);
}

extern "C" void kernel_launch(void* const* d_in, const int* in_sizes, int n_in,
                              void* d_out, int out_size, void* d_ws, size_t ws_size,
                              hipStream_t stream) {
  const float* Q = (const float*)d_in[0];          // [4096,128]
  const float* K = (const float*)d_in[1];          // [8192,128]
  const float* W = (const float*)d_in[2];          // [4096,8192]
  float* out = (float*)d_out;                      // [4096,128]

  unsigned short* Qs   = (unsigned short*)d_ws;               // 1 MB
  unsigned short* Kswz = Qs + (size_t)Qn * Dn;                // 2 MB
  unsigned short* Vswz = Kswz + (size_t)Mn * Dn;              // 2 MB
  float* Oacc = (float*)(Vswz + (size_t)Mn * Dn);             // 2 MB
  float* Lacc = Oacc + (size_t)Qn * Dn;                       // 16 KB (total 7.02 MB)

  int n4 = (Qn * Dn + Qn) / 4;                                // Oacc + Lacc zeroing
  zero_kernel<<<(n4 + 255) / 256, 256, 0, stream>>>((float4*)Oacc, n4);

  cast_q<<<(Qn * Dn / 4) / 256, 256, 0, stream>>>((const float4*)Q, (ushort4*)Qs);
  swz_kernel<<<dim3(Mn / 64, Dn / 64), 256, 0, stream>>>(K, Kswz, Vswz);
  attn_kernel<<<(Qn / QB) * MSPLIT, 256, 0, stream>>>(W, Qs, Kswz, Vswz, Oacc, Lacc);
  finalize_kernel<<<(Qn * Dn / 4) / 256, 256, 0, stream>>>(
      (const float4*)Oacc, Lacc, (float4*)out);
}